// Round 8
// baseline (155.199 us; speedup 1.0000x reference)
//
#include <hip/hip_runtime.h>
#include <math.h>

#define T_LEN 6000
#define NROWS 4096          // B*C = 512*8
#define NCH 8
#define F_BINS 129
#define CF (NCH*F_BINS)     // 1032
#define REG_EPS 1e-7f

typedef _Float16 half8 __attribute__((ext_vector_type(8)));
typedef _Float16 half4_t __attribute__((ext_vector_type(4)));
typedef float f32x4 __attribute__((ext_vector_type(4)));

// ---------------- Kernel A: DFT basis (row-independent), Bt[n][k] f16 ----------------
__global__ __launch_bounds__(256) void basis_kernel(_Float16* __restrict__ Bt) {
  int n = blockIdx.x;        // 0..255
  int k = threadIdx.x;       // 0..255
  int m = (n < 129) ? ((n * k) & 255) : (((n - 128) * k) & 255);
  float ang = (float)m * (6.283185307179586f / 256.f);
  float v = (n < 129) ? cosf(ang) : sinf(ang);
  Bt[(n << 8) | k] = (_Float16)v;
}

// ---------------- Kernel B: Welch PSD + row mean via im2col MFMA GEMM ----------------
// Per row: A[m][k]=x[128m+k] (M=48 tiles of 16, m<45 valid; K=256), B[k][n]=DFT basis
// (N=256: cos 0..128, sin 129..255). psd[f] = (sum_m Re^2+Im^2) scaled.
// 4 waves x 4 N-tiles. B fragments loaded from global PER USE (L2-resident 128 KB)
// -- round-7's persistent-B spilled to scratch (128 VGPRs of B alone). Live set now
// ~115 VGPR -> no spill at the (256,4) 128-cap. PSD_ROWS=2 -> grid 2048 -> 4 blocks/CU.
// A staged as f16 in LDS, XOR-swizzled byte^=((byte>>8)&7)<<4 (2 lanes/bank-group).
// Detrend only affects bin 0 -> psd[0]=REG_EPS. Mask m>=45 in the square-accumulate.
#define PSD_ROWS 2
__global__ __launch_bounds__(256, 4) void psd_kernel(const float* __restrict__ x,
                                                     const _Float16* __restrict__ Bt,
                                                     float* __restrict__ psd,
                                                     float* __restrict__ means) {
  int tid = threadIdx.x;
  int lane = tid & 63;
  int w = tid >> 6;          // 0..3
  int l15 = lane & 15, l4 = lane >> 4;
  __shared__ __align__(16) _Float16 xh[6272];
  __shared__ float colsum[256];
  __shared__ float rowm[4];

  // per-wave B base pointers (col n = 16*(4w+i)+l15, k-slice base 8*l4)
  const _Float16* bb0 = Bt + (((16 * (4 * w + 0) + l15) << 8) + 8 * l4);
  const _Float16* bb1 = Bt + (((16 * (4 * w + 1) + l15) << 8) + 8 * l4);
  const _Float16* bb2 = Bt + (((16 * (4 * w + 2) + l15) << 8) + 8 * l4);
  const _Float16* bb3 = Bt + (((16 * (4 * w + 3) + l15) << 8) + 8 * l4);

  int r0 = blockIdx.x * PSD_ROWS;
  for (int jr = 0; jr < PSD_ROWS; ++jr) {
    int r = r0 + jr;
    const float* xr = x + (size_t)r * T_LEN;
    // ---- stage row to f16 LDS (swizzled writes), accumulate row sum ----
    float rsum = 0.f;
    #pragma unroll
    for (int j = 0; j < 7; ++j) {
      int c = tid + 256 * j;                    // float4 chunk index
      if (c < 1568) {
        float4 v = (c < 1500) ? ((const float4*)xr)[c]
                              : make_float4(0.f, 0.f, 0.f, 0.f);
        rsum += v.x + v.y + v.z + v.w;
        half4_t h = { (_Float16)v.x, (_Float16)v.y, (_Float16)v.z, (_Float16)v.w };
        int byte = 8 * c;
        byte ^= ((byte >> 8) & 7) << 4;
        *(half4_t*)((char*)xh + byte) = h;
      }
    }
    __syncthreads();                            // (A) stage visible
    // ---- GEMM ----
    f32x4 acc[4][3];
    #pragma unroll
    for (int i = 0; i < 4; ++i)
      #pragma unroll
      for (int mt = 0; mt < 3; ++mt)
        acc[i][mt] = (f32x4){0.f, 0.f, 0.f, 0.f};
    #pragma unroll
    for (int kk = 0; kk < 8; ++kk) {
      half8 a[3];
      #pragma unroll
      for (int mt = 0; mt < 3; ++mt) {
        int ab = 4096 * mt + 256 * l15 + 64 * kk + 16 * l4;
        ab ^= ((ab >> 8) & 7) << 4;
        a[mt] = *(const half8*)((const char*)xh + ab);
      }
      half8 b0 = *(const half8*)(bb0 + 32 * kk);
      half8 b1 = *(const half8*)(bb1 + 32 * kk);
      half8 b2 = *(const half8*)(bb2 + 32 * kk);
      half8 b3 = *(const half8*)(bb3 + 32 * kk);
      #pragma unroll
      for (int mt = 0; mt < 3; ++mt) {
        acc[0][mt] = __builtin_amdgcn_mfma_f32_16x16x32_f16(a[mt], b0, acc[0][mt], 0, 0, 0);
        acc[1][mt] = __builtin_amdgcn_mfma_f32_16x16x32_f16(a[mt], b1, acc[1][mt], 0, 0, 0);
        acc[2][mt] = __builtin_amdgcn_mfma_f32_16x16x32_f16(a[mt], b2, acc[2][mt], 0, 0, 0);
        acc[3][mt] = __builtin_amdgcn_mfma_f32_16x16x32_f16(a[mt], b3, acc[3][mt], 0, 0, 0);
      }
    }
    // row-sum reduce (registers only; written to LDS after barrier B)
    #pragma unroll
    for (int off = 32; off >= 1; off >>= 1) rsum += __shfl_xor(rsum, off);
    // per-lane column partials; C/D: row m = 16*mt+4*l4+j, col n = 16*nt+l15
    float s0, s1, s2, s3;
    #pragma unroll
    for (int i = 0; i < 4; ++i) {
      float t = 0.f;
      #pragma unroll
      for (int j = 0; j < 4; ++j) {
        t += acc[i][0][j] * acc[i][0][j];
        t += acc[i][1][j] * acc[i][1][j];
        if (4 * l4 + j < 13) t += acc[i][2][j] * acc[i][2][j];  // mask m>=45
      }
      t += __shfl_xor(t, 16);
      t += __shfl_xor(t, 32);
      if (i == 0) s0 = t; else if (i == 1) s1 = t; else if (i == 2) s2 = t; else s3 = t;
    }
    __syncthreads();                            // (B) xh & prev colsum reads done
    if (l4 == 0) {
      colsum[16 * (4 * w + 0) + l15] = s0;
      colsum[16 * (4 * w + 1) + l15] = s1;
      colsum[16 * (4 * w + 2) + l15] = s2;
      colsum[16 * (4 * w + 3) + l15] = s3;
    }
    if (lane == 0) rowm[w] = rsum;
    __syncthreads();                            // (C)
    if (tid < F_BINS) {
      float v;
      if (tid == 0) v = 0.f;                                    // detrended DC
      else if (tid == 128) v = colsum[128] * (1.f / 11520.f);   // Nyquist, no doubling
      else v = (colsum[tid] + colsum[tid + 128]) * (1.f / 5760.f);
      psd[(size_t)r * F_BINS + tid] = v + REG_EPS;
    }
    if (tid == 0)
      means[r] = (rowm[0] + rowm[1] + rowm[2] + rowm[3]) * (1.f / (float)T_LEN);
  }
}

// ---------------- Kernel C: barycenter over batch (unchanged) ----------------
__global__ __launch_bounds__(256) void bary_kernel(const float* __restrict__ psd,
                                                   float* __restrict__ bary) {
  int cf = blockIdx.x;
  int tid = threadIdx.x;
  float s = sqrtf(psd[(size_t)tid * CF + cf]) +
            sqrtf(psd[(size_t)(tid + 256) * CF + cf]);
  #pragma unroll
  for (int off = 32; off >= 1; off >>= 1) s += __shfl_down(s, off);
  __shared__ float wsum[4];
  if ((tid & 63) == 0) wsum[tid >> 6] = s;
  __syncthreads();
  if (tid == 0) {
    float tot = (wsum[0] + wsum[1] + wsum[2] + wsum[3]) * (1.f / (float)F_BINS);
    bary[cf] = tot * tot;
  }
}

// ---------------- Kernel D: filter H (unchanged) ----------------
__global__ __launch_bounds__(256) void filt_kernel(const float* __restrict__ psd,
                                                   const float* __restrict__ bary,
                                                   float* __restrict__ H) {
  int rc = blockIdx.x;
  int c = rc & (NCH - 1);
  int t = threadIdx.x;
  __shared__ float dv[F_BINS];
  __shared__ float hv[F_BINS];
  if (t < F_BINS)
    dv[t] = sqrtf(bary[c * F_BINS + t] / psd[(size_t)rc * F_BINS + t]);
  __syncthreads();
  if (t < F_BINS) {
    float ct, st;
    __sincosf(6.283185307179586f * (float)t * (1.f / 256.f), &st, &ct);
    float cr = ct, ci = st;
    float acc = 0.f;
    for (int k = 1; k <= 127; ++k) {
      acc = fmaf(dv[k], cr, acc);
      float nr = cr * ct - ci * st;
      ci = cr * st + ci * ct;
      cr = nr;
    }
    float val = dv[0] + ((t & 1) ? -dv[128] : dv[128]) + 2.f * acc;
    hv[t] = val * (1.f / 256.f);
  }
  __syncthreads();
  int idx = t - 127; if (idx < 0) idx = -idx;
  H[(size_t)rc * 256 + t] = hv[idx];
}

// ---------------- Kernel E: depthwise conv as per-row im2col MFMA GEMM (unchanged) ----------------
#define XH_N 6528
#define BSTRIDE 296
__global__ __launch_bounds__(384, 1) void conv_kernel(const float* __restrict__ x,
                                                      const float* __restrict__ means,
                                                      const float* __restrict__ Hg,
                                                      float* __restrict__ y) {
  int rc = blockIdx.x;
  int tid = threadIdx.x;
  int lane = tid & 63;
  int w = tid >> 6;
  __shared__ __align__(16) _Float16 xh[XH_N];
  __shared__ __align__(16) _Float16 Bp[16 * BSTRIDE];
  const float* xr = x + (size_t)rc * T_LEN;
  const float* Hrow = Hg + (size_t)rc * 256;
  float mean = means[rc];
  for (int f = tid; f < XH_N; f += 384) {
    int g = f - 127;
    float v = (g >= 0 && g < T_LEN) ? (xr[g] - mean) : 0.f;
    xh[f] = (_Float16)v;
  }
  for (int idx = tid; idx < 16 * 288; idx += 384) {
    int n = idx / 288;
    int k = idx - n * 288;
    int s = k - n;
    float v = (s >= 0 && s < 256) ? Hrow[s] : 0.f;
    Bp[n * BSTRIDE + k] = (_Float16)v;
  }
  __syncthreads();

  int l15 = lane & 15, l4 = lane >> 4;
  f32x4 acc0 = {0.f,0.f,0.f,0.f}, acc1 = {0.f,0.f,0.f,0.f};
  f32x4 acc2 = {0.f,0.f,0.f,0.f}, acc3 = {0.f,0.f,0.f,0.f};
  const _Float16* bbase = &Bp[BSTRIDE * l15 + 8 * l4];
  const _Float16* abase = &xh[16 * l15 + 8 * l4 + 1024 * w];
  #pragma unroll
  for (int kk = 0; kk < 9; ++kk) {
    half8 b = *(const half8*)(bbase + 32 * kk);
    half8 a0 = *(const half8*)(abase + 32 * kk);
    half8 a1 = *(const half8*)(abase + 256 + 32 * kk);
    half8 a2 = *(const half8*)(abase + 512 + 32 * kk);
    half8 a3 = *(const half8*)(abase + 768 + 32 * kk);
    acc0 = __builtin_amdgcn_mfma_f32_16x16x32_f16(a0, b, acc0, 0, 0, 0);
    acc1 = __builtin_amdgcn_mfma_f32_16x16x32_f16(a1, b, acc1, 0, 0, 0);
    acc2 = __builtin_amdgcn_mfma_f32_16x16x32_f16(a2, b, acc2, 0, 0, 0);
    acc3 = __builtin_amdgcn_mfma_f32_16x16x32_f16(a3, b, acc3, 0, 0, 0);
  }
  float* yr = y + (size_t)rc * T_LEN;
  #pragma unroll
  for (int i = 0; i < 4; ++i) {
    f32x4 a = (i == 0) ? acc0 : (i == 1) ? acc1 : (i == 2) ? acc2 : acc3;
    int mt = 4 * w + i;
    #pragma unroll
    for (int j = 0; j < 4; ++j) {
      int m = 16 * mt + 4 * l4 + j;
      if (m < 375) yr[16 * m + l15] = a[j];
    }
  }
}

extern "C" void kernel_launch(void* const* d_in, const int* in_sizes, int n_in,
                              void* d_out, int out_size, void* d_ws, size_t ws_size,
                              hipStream_t stream) {
  const float* x = (const float*)d_in[0];
  float* out = (float*)d_out;
  float* psd   = (float*)d_ws;                         //   528,384 f
  float* bary  = psd + (size_t)NROWS * F_BINS;         //     1,032 f
  float* H     = bary + CF;                            // 1,048,576 f
  float* means = H + (size_t)NROWS * 256;              //     4,096 f
  _Float16* Bt = (_Float16*)(means + NROWS);           //    65,536 f16 (16B-aligned)
  basis_kernel<<<256, 256, 0, stream>>>(Bt);
  psd_kernel<<<NROWS / PSD_ROWS, 256, 0, stream>>>(x, Bt, psd, means);
  bary_kernel<<<CF, 256, 0, stream>>>(psd, bary);
  filt_kernel<<<NROWS, 256, 0, stream>>>(psd, bary, H);
  conv_kernel<<<NROWS, 384, 0, stream>>>(x, means, H, out);
}

// Round 9
// 134.120 us; speedup vs baseline: 1.1572x; 1.1572x over previous
//
#include <hip/hip_runtime.h>
#include <math.h>

#define T_LEN 6000
#define NROWS 4096          // B*C = 512*8
#define NCH 8
#define F_BINS 129
#define CF (NCH*F_BINS)     // 1032
#define REG_EPS 1e-7f

typedef _Float16 half8 __attribute__((ext_vector_type(8)));
typedef _Float16 half4_t __attribute__((ext_vector_type(4)));
typedef float f32x4 __attribute__((ext_vector_type(4)));

// ---------------- Kernel A: DFT basis, pre-packed in MFMA B-fragment layout ----------------
// Bf[((nt*8+kk)*64+lane)] is a half8: element e -> B[k][n] with n=16*nt+(lane&15),
// k=32*kk+8*(lane>>4)+e. n<129: cos(2*pi*n*k/256); n>=129: sin(2*pi*(n-128)*k/256).
// Same fragment convention as the A-side (8 contiguous k per lane), so any within-K
// hardware permutation cancels between A and B.
__global__ __launch_bounds__(256) void basis_kernel(_Float16* __restrict__ Bf) {
  int g = blockIdx.x * 256 + threadIdx.x;   // 0..8191 = (nt*8+kk)*64+lane
  int lane = g & 63;
  int ntkk = g >> 6;
  int nt = ntkk >> 3, kk = ntkk & 7;
  int n = 16 * nt + (lane & 15);
  int k0 = 32 * kk + 8 * (lane >> 4);
  half8 out;
  #pragma unroll
  for (int e = 0; e < 8; ++e) {
    int k = k0 + e;
    int m = (n < 129) ? ((n * k) & 255) : (((n - 128) * k) & 255);
    float ang = (float)m * (6.283185307179586f / 256.f);
    float v = (n < 129) ? cosf(ang) : sinf(ang);
    out[e] = (_Float16)v;
  }
  *(half8*)(Bf + (size_t)g * 8) = out;
}

// ---------------- Kernel B: Welch PSD + row mean via im2col MFMA GEMM ----------------
// 8 waves; wave w owns N-tiles {2w, 2w+1}; bf[2][8] (64 VGPR) loaded ONCE per block
// from the fragment-packed Bf (coalesced 1KB/wave loads), reused for PSD_ROWS rows.
// A[m][k]=x[128m+k] staged f16 in LDS, XOR-swizzled byte^=((byte>>8)&7)<<4.
// Detrend only affects bin 0 -> psd[0]=REG_EPS. Mask m>=45 in the square-accumulate.
#define PSD_ROWS 4
__global__ __launch_bounds__(512, 2) void psd_kernel(const float* __restrict__ x,
                                                     const _Float16* __restrict__ Bf,
                                                     float* __restrict__ psd,
                                                     float* __restrict__ means) {
  int tid = threadIdx.x;
  int lane = tid & 63;
  int w = tid >> 6;          // 0..7
  int l15 = lane & 15, l4 = lane >> 4;
  __shared__ __align__(16) _Float16 xh[6272];
  __shared__ float colsum[256];
  __shared__ float rowm[8];

  // persistent B fragments: nt = 2w+i
  half8 bf[2][8];
  #pragma unroll
  for (int i = 0; i < 2; ++i) {
    const _Float16* bb = Bf + (size_t)(((2 * w + i) * 8) * 64 + lane) * 8;
    #pragma unroll
    for (int kk = 0; kk < 8; ++kk)
      bf[i][kk] = *(const half8*)(bb + (size_t)kk * 512);
  }

  int r0 = blockIdx.x * PSD_ROWS;
  for (int jr = 0; jr < PSD_ROWS; ++jr) {
    int r = r0 + jr;
    const float* xr = x + (size_t)r * T_LEN;
    // ---- stage row to f16 LDS (swizzled writes), accumulate row sum ----
    float rsum = 0.f;
    #pragma unroll
    for (int j = 0; j < 4; ++j) {
      int c = tid + 512 * j;                    // float4 chunk index
      if (c < 1568) {
        float4 v = (c < 1500) ? ((const float4*)xr)[c]
                              : make_float4(0.f, 0.f, 0.f, 0.f);
        rsum += v.x + v.y + v.z + v.w;
        half4_t h = { (_Float16)v.x, (_Float16)v.y, (_Float16)v.z, (_Float16)v.w };
        int byte = 8 * c;
        byte ^= ((byte >> 8) & 7) << 4;
        *(half4_t*)((char*)xh + byte) = h;
      }
    }
    __syncthreads();                            // (A) stage visible
    // ---- GEMM ----
    f32x4 acc[2][3];
    #pragma unroll
    for (int i = 0; i < 2; ++i)
      #pragma unroll
      for (int mt = 0; mt < 3; ++mt)
        acc[i][mt] = (f32x4){0.f, 0.f, 0.f, 0.f};
    #pragma unroll
    for (int kk = 0; kk < 8; ++kk) {
      half8 a[3];
      #pragma unroll
      for (int mt = 0; mt < 3; ++mt) {
        int ab = 4096 * mt + 256 * l15 + 64 * kk + 16 * l4;
        ab ^= ((ab >> 8) & 7) << 4;
        a[mt] = *(const half8*)((const char*)xh + ab);
      }
      #pragma unroll
      for (int mt = 0; mt < 3; ++mt) {
        acc[0][mt] = __builtin_amdgcn_mfma_f32_16x16x32_f16(a[mt], bf[0][kk], acc[0][mt], 0, 0, 0);
        acc[1][mt] = __builtin_amdgcn_mfma_f32_16x16x32_f16(a[mt], bf[1][kk], acc[1][mt], 0, 0, 0);
      }
    }
    // row-sum reduce (registers only; written to LDS after barrier B)
    #pragma unroll
    for (int off = 32; off >= 1; off >>= 1) rsum += __shfl_xor(rsum, off);
    // per-lane column partials; C/D: row m = 16*mt+4*l4+j, col n = 16*nt+l15
    float s0, s1;
    #pragma unroll
    for (int i = 0; i < 2; ++i) {
      float t = 0.f;
      #pragma unroll
      for (int j = 0; j < 4; ++j) {
        t += acc[i][0][j] * acc[i][0][j];
        t += acc[i][1][j] * acc[i][1][j];
        if (4 * l4 + j < 13) t += acc[i][2][j] * acc[i][2][j];  // mask m>=45
      }
      t += __shfl_xor(t, 16);
      t += __shfl_xor(t, 32);
      if (i == 0) s0 = t; else s1 = t;
    }
    __syncthreads();                            // (B) xh & prev colsum reads done
    if (l4 == 0) {
      colsum[16 * (2 * w + 0) + l15] = s0;
      colsum[16 * (2 * w + 1) + l15] = s1;
    }
    if (lane == 0) rowm[w] = rsum;
    __syncthreads();                            // (C)
    if (tid < F_BINS) {
      float v;
      if (tid == 0) v = 0.f;                                    // detrended DC
      else if (tid == 128) v = colsum[128] * (1.f / 11520.f);   // Nyquist, no doubling
      else v = (colsum[tid] + colsum[tid + 128]) * (1.f / 5760.f);
      psd[(size_t)r * F_BINS + tid] = v + REG_EPS;
    }
    if (tid == 0) {
      float ms = 0.f;
      #pragma unroll
      for (int q = 0; q < 8; ++q) ms += rowm[q];
      means[r] = ms * (1.f / (float)T_LEN);
    }
  }
}

// ---------------- Kernel C: barycenter over batch (unchanged) ----------------
__global__ __launch_bounds__(256) void bary_kernel(const float* __restrict__ psd,
                                                   float* __restrict__ bary) {
  int cf = blockIdx.x;
  int tid = threadIdx.x;
  float s = sqrtf(psd[(size_t)tid * CF + cf]) +
            sqrtf(psd[(size_t)(tid + 256) * CF + cf]);
  #pragma unroll
  for (int off = 32; off >= 1; off >>= 1) s += __shfl_down(s, off);
  __shared__ float wsum[4];
  if ((tid & 63) == 0) wsum[tid >> 6] = s;
  __syncthreads();
  if (tid == 0) {
    float tot = (wsum[0] + wsum[1] + wsum[2] + wsum[3]) * (1.f / (float)F_BINS);
    bary[cf] = tot * tot;
  }
}

// ---------------- Kernel D: filter H (unchanged) ----------------
__global__ __launch_bounds__(256) void filt_kernel(const float* __restrict__ psd,
                                                   const float* __restrict__ bary,
                                                   float* __restrict__ H) {
  int rc = blockIdx.x;
  int c = rc & (NCH - 1);
  int t = threadIdx.x;
  __shared__ float dv[F_BINS];
  __shared__ float hv[F_BINS];
  if (t < F_BINS)
    dv[t] = sqrtf(bary[c * F_BINS + t] / psd[(size_t)rc * F_BINS + t]);
  __syncthreads();
  if (t < F_BINS) {
    float ct, st;
    __sincosf(6.283185307179586f * (float)t * (1.f / 256.f), &st, &ct);
    float cr = ct, ci = st;
    float acc = 0.f;
    for (int k = 1; k <= 127; ++k) {
      acc = fmaf(dv[k], cr, acc);
      float nr = cr * ct - ci * st;
      ci = cr * st + ci * ct;
      cr = nr;
    }
    float val = dv[0] + ((t & 1) ? -dv[128] : dv[128]) + 2.f * acc;
    hv[t] = val * (1.f / 256.f);
  }
  __syncthreads();
  int idx = t - 127; if (idx < 0) idx = -idx;
  H[(size_t)rc * 256 + t] = hv[idx];
}

// ---------------- Kernel E: depthwise conv as per-row im2col MFMA GEMM (unchanged) ----------------
#define XH_N 6528
#define BSTRIDE 296
__global__ __launch_bounds__(384, 1) void conv_kernel(const float* __restrict__ x,
                                                      const float* __restrict__ means,
                                                      const float* __restrict__ Hg,
                                                      float* __restrict__ y) {
  int rc = blockIdx.x;
  int tid = threadIdx.x;
  int lane = tid & 63;
  int w = tid >> 6;
  __shared__ __align__(16) _Float16 xh[XH_N];
  __shared__ __align__(16) _Float16 Bp[16 * BSTRIDE];
  const float* xr = x + (size_t)rc * T_LEN;
  const float* Hrow = Hg + (size_t)rc * 256;
  float mean = means[rc];
  for (int f = tid; f < XH_N; f += 384) {
    int g = f - 127;
    float v = (g >= 0 && g < T_LEN) ? (xr[g] - mean) : 0.f;
    xh[f] = (_Float16)v;
  }
  for (int idx = tid; idx < 16 * 288; idx += 384) {
    int n = idx / 288;
    int k = idx - n * 288;
    int s = k - n;
    float v = (s >= 0 && s < 256) ? Hrow[s] : 0.f;
    Bp[n * BSTRIDE + k] = (_Float16)v;
  }
  __syncthreads();

  int l15 = lane & 15, l4 = lane >> 4;
  f32x4 acc0 = {0.f,0.f,0.f,0.f}, acc1 = {0.f,0.f,0.f,0.f};
  f32x4 acc2 = {0.f,0.f,0.f,0.f}, acc3 = {0.f,0.f,0.f,0.f};
  const _Float16* bbase = &Bp[BSTRIDE * l15 + 8 * l4];
  const _Float16* abase = &xh[16 * l15 + 8 * l4 + 1024 * w];
  #pragma unroll
  for (int kk = 0; kk < 9; ++kk) {
    half8 b = *(const half8*)(bbase + 32 * kk);
    half8 a0 = *(const half8*)(abase + 32 * kk);
    half8 a1 = *(const half8*)(abase + 256 + 32 * kk);
    half8 a2 = *(const half8*)(abase + 512 + 32 * kk);
    half8 a3 = *(const half8*)(abase + 768 + 32 * kk);
    acc0 = __builtin_amdgcn_mfma_f32_16x16x32_f16(a0, b, acc0, 0, 0, 0);
    acc1 = __builtin_amdgcn_mfma_f32_16x16x32_f16(a1, b, acc1, 0, 0, 0);
    acc2 = __builtin_amdgcn_mfma_f32_16x16x32_f16(a2, b, acc2, 0, 0, 0);
    acc3 = __builtin_amdgcn_mfma_f32_16x16x32_f16(a3, b, acc3, 0, 0, 0);
  }
  float* yr = y + (size_t)rc * T_LEN;
  #pragma unroll
  for (int i = 0; i < 4; ++i) {
    f32x4 a = (i == 0) ? acc0 : (i == 1) ? acc1 : (i == 2) ? acc2 : acc3;
    int mt = 4 * w + i;
    #pragma unroll
    for (int j = 0; j < 4; ++j) {
      int m = 16 * mt + 4 * l4 + j;
      if (m < 375) yr[16 * m + l15] = a[j];
    }
  }
}

extern "C" void kernel_launch(void* const* d_in, const int* in_sizes, int n_in,
                              void* d_out, int out_size, void* d_ws, size_t ws_size,
                              hipStream_t stream) {
  const float* x = (const float*)d_in[0];
  float* out = (float*)d_out;
  float* psd   = (float*)d_ws;                         //   528,384 f
  float* bary  = psd + (size_t)NROWS * F_BINS;         //     1,032 f
  float* H     = bary + CF;                            // 1,048,576 f
  float* means = H + (size_t)NROWS * 256;              //     4,096 f
  _Float16* Bf = (_Float16*)(means + NROWS);           //    65,536 f16 (16B-aligned)
  basis_kernel<<<32, 256, 0, stream>>>(Bf);
  psd_kernel<<<NROWS / PSD_ROWS, 512, 0, stream>>>(x, Bf, psd, means);
  bary_kernel<<<CF, 256, 0, stream>>>(psd, bary);
  filt_kernel<<<NROWS, 256, 0, stream>>>(psd, bary, H);
  conv_kernel<<<NROWS, 384, 0, stream>>>(x, means, H, out);
}

// Round 10
// 129.513 us; speedup vs baseline: 1.1983x; 1.0356x over previous
//
#include <hip/hip_runtime.h>
#include <math.h>

#define T_LEN 6000
#define NROWS 4096          // B*C = 512*8
#define NCH 8
#define F_BINS 129
#define CF (NCH*F_BINS)     // 1032
#define REG_EPS 1e-7f

typedef _Float16 half8 __attribute__((ext_vector_type(8)));
typedef _Float16 half4_t __attribute__((ext_vector_type(4)));
typedef float f32x4 __attribute__((ext_vector_type(4)));

// ---------------- Kernel A: DFT basis, pre-packed in MFMA B-fragment layout ----------------
// Bf[((nt*8+kk)*64+lane)] is a half8: element e -> B[k][n] with n=16*nt+(lane&15),
// k=32*kk+8*(lane>>4)+e. n<129: cos(2*pi*n*k/256); n>=129: sin(2*pi*(n-128)*k/256).
__global__ __launch_bounds__(256) void basis_kernel(_Float16* __restrict__ Bf) {
  int g = blockIdx.x * 256 + threadIdx.x;   // 0..8191 = (nt*8+kk)*64+lane
  int lane = g & 63;
  int ntkk = g >> 6;
  int nt = ntkk >> 3, kk = ntkk & 7;
  int n = 16 * nt + (lane & 15);
  int k0 = 32 * kk + 8 * (lane >> 4);
  half8 out;
  #pragma unroll
  for (int e = 0; e < 8; ++e) {
    int k = k0 + e;
    int m = (n < 129) ? ((n * k) & 255) : (((n - 128) * k) & 255);
    float ang = (float)m * (6.283185307179586f / 256.f);
    float v = (n < 129) ? cosf(ang) : sinf(ang);
    out[e] = (_Float16)v;
  }
  *(half8*)(Bf + (size_t)g * 8) = out;
}

// ---------------- Kernel B: Welch PSD + row mean via im2col MFMA GEMM ----------------
// 8 waves; wave w owns N-tiles {2w,2w+1}; bf[2][8] persistent (loaded once/block).
// T14 async-STAGE: row jr staged from registers; row jr+1's global loads are issued
// BEFORE the barrier so their HBM latency hides under GEMM(jr)+epilogue(jr).
#define PSD_ROWS 4
__global__ __launch_bounds__(512, 2) void psd_kernel(const float* __restrict__ x,
                                                     const _Float16* __restrict__ Bf,
                                                     float* __restrict__ psd,
                                                     float* __restrict__ means) {
  int tid = threadIdx.x;
  int lane = tid & 63;
  int w = tid >> 6;          // 0..7
  int l15 = lane & 15, l4 = lane >> 4;
  __shared__ __align__(16) _Float16 xh[6272];
  __shared__ float colsum[256];
  __shared__ float rowm[8];

  // persistent B fragments: nt = 2w+i (coalesced fragment-layout loads)
  half8 bf[2][8];
  #pragma unroll
  for (int i = 0; i < 2; ++i) {
    const _Float16* bb = Bf + (size_t)(((2 * w + i) * 8) * 64 + lane) * 8;
    #pragma unroll
    for (int kk = 0; kk < 8; ++kk)
      bf[i][kk] = *(const half8*)(bb + (size_t)kk * 512);
  }

  int r0 = blockIdx.x * PSD_ROWS;
  // prologue: load row r0 into registers
  float4 v[4];
  {
    const float* xr = x + (size_t)r0 * T_LEN;
    #pragma unroll
    for (int j = 0; j < 4; ++j) {
      int c = tid + 512 * j;
      v[j] = (c < 1500) ? ((const float4*)xr)[c] : make_float4(0.f, 0.f, 0.f, 0.f);
    }
  }

  for (int jr = 0; jr < PSD_ROWS; ++jr) {
    int r = r0 + jr;
    // ---- stage row jr from regs to f16 LDS (swizzled), accumulate row sum ----
    float rsum = 0.f;
    #pragma unroll
    for (int j = 0; j < 4; ++j) {
      int c = tid + 512 * j;
      if (c < 1568) {
        float4 q = v[j];
        rsum += q.x + q.y + q.z + q.w;
        half4_t h = { (_Float16)q.x, (_Float16)q.y, (_Float16)q.z, (_Float16)q.w };
        int byte = 8 * c;
        byte ^= ((byte >> 8) & 7) << 4;
        *(half4_t*)((char*)xh + byte) = h;
      }
    }
    // ---- early-issue next row's loads (before barrier: HBM latency hides under GEMM) ----
    if (jr + 1 < PSD_ROWS) {
      const float* xn = x + (size_t)(r + 1) * T_LEN;
      #pragma unroll
      for (int j = 0; j < 4; ++j) {
        int c = tid + 512 * j;
        v[j] = (c < 1500) ? ((const float4*)xn)[c] : make_float4(0.f, 0.f, 0.f, 0.f);
      }
    }
    __syncthreads();                            // (A) stage visible
    // ---- GEMM ----
    f32x4 acc[2][3];
    #pragma unroll
    for (int i = 0; i < 2; ++i)
      #pragma unroll
      for (int mt = 0; mt < 3; ++mt)
        acc[i][mt] = (f32x4){0.f, 0.f, 0.f, 0.f};
    #pragma unroll
    for (int kk = 0; kk < 8; ++kk) {
      half8 a[3];
      #pragma unroll
      for (int mt = 0; mt < 3; ++mt) {
        int ab = 4096 * mt + 256 * l15 + 64 * kk + 16 * l4;
        ab ^= ((ab >> 8) & 7) << 4;
        a[mt] = *(const half8*)((const char*)xh + ab);
      }
      #pragma unroll
      for (int mt = 0; mt < 3; ++mt) {
        acc[0][mt] = __builtin_amdgcn_mfma_f32_16x16x32_f16(a[mt], bf[0][kk], acc[0][mt], 0, 0, 0);
        acc[1][mt] = __builtin_amdgcn_mfma_f32_16x16x32_f16(a[mt], bf[1][kk], acc[1][mt], 0, 0, 0);
      }
    }
    // row-sum reduce
    #pragma unroll
    for (int off = 32; off >= 1; off >>= 1) rsum += __shfl_xor(rsum, off);
    // per-lane column partials; C/D: row m = 16*mt+4*l4+j, col n = 16*nt+l15
    float s0, s1;
    #pragma unroll
    for (int i = 0; i < 2; ++i) {
      float t = 0.f;
      #pragma unroll
      for (int j = 0; j < 4; ++j) {
        t += acc[i][0][j] * acc[i][0][j];
        t += acc[i][1][j] * acc[i][1][j];
        if (4 * l4 + j < 13) t += acc[i][2][j] * acc[i][2][j];  // mask m>=45
      }
      t += __shfl_xor(t, 16);
      t += __shfl_xor(t, 32);
      if (i == 0) s0 = t; else s1 = t;
    }
    __syncthreads();                            // (B) xh & prev colsum reads done
    if (l4 == 0) {
      colsum[16 * (2 * w + 0) + l15] = s0;
      colsum[16 * (2 * w + 1) + l15] = s1;
    }
    if (lane == 0) rowm[w] = rsum;
    __syncthreads();                            // (C)
    if (tid < F_BINS) {
      float vv;
      if (tid == 0) vv = 0.f;                                   // detrended DC
      else if (tid == 128) vv = colsum[128] * (1.f / 11520.f);  // Nyquist, no doubling
      else vv = (colsum[tid] + colsum[tid + 128]) * (1.f / 5760.f);
      psd[(size_t)r * F_BINS + tid] = vv + REG_EPS;
    }
    if (tid == 0) {
      float ms = 0.f;
      #pragma unroll
      for (int q = 0; q < 8; ++q) ms += rowm[q];
      means[r] = ms * (1.f / (float)T_LEN);
    }
  }
}

// ---------------- Kernel C: barycenter over batch (unchanged) ----------------
__global__ __launch_bounds__(256) void bary_kernel(const float* __restrict__ psd,
                                                   float* __restrict__ bary) {
  int cf = blockIdx.x;
  int tid = threadIdx.x;
  float s = sqrtf(psd[(size_t)tid * CF + cf]) +
            sqrtf(psd[(size_t)(tid + 256) * CF + cf]);
  #pragma unroll
  for (int off = 32; off >= 1; off >>= 1) s += __shfl_down(s, off);
  __shared__ float wsum[4];
  if ((tid & 63) == 0) wsum[tid >> 6] = s;
  __syncthreads();
  if (tid == 0) {
    float tot = (wsum[0] + wsum[1] + wsum[2] + wsum[3]) * (1.f / (float)F_BINS);
    bary[cf] = tot * tot;
  }
}

// ---------------- Kernel D: filter H (unchanged) ----------------
__global__ __launch_bounds__(256) void filt_kernel(const float* __restrict__ psd,
                                                   const float* __restrict__ bary,
                                                   float* __restrict__ H) {
  int rc = blockIdx.x;
  int c = rc & (NCH - 1);
  int t = threadIdx.x;
  __shared__ float dv[F_BINS];
  __shared__ float hv[F_BINS];
  if (t < F_BINS)
    dv[t] = sqrtf(bary[c * F_BINS + t] / psd[(size_t)rc * F_BINS + t]);
  __syncthreads();
  if (t < F_BINS) {
    float ct, st;
    __sincosf(6.283185307179586f * (float)t * (1.f / 256.f), &st, &ct);
    float cr = ct, ci = st;
    float acc = 0.f;
    for (int k = 1; k <= 127; ++k) {
      acc = fmaf(dv[k], cr, acc);
      float nr = cr * ct - ci * st;
      ci = cr * st + ci * ct;
      cr = nr;
    }
    float val = dv[0] + ((t & 1) ? -dv[128] : dv[128]) + 2.f * acc;
    hv[t] = val * (1.f / 256.f);
  }
  __syncthreads();
  int idx = t - 127; if (idx < 0) idx = -idx;
  H[(size_t)rc * 256 + t] = hv[idx];
}

// ---------------- Kernel E: depthwise conv as per-row im2col MFMA GEMM ----------------
// Shift-by-one im2col for vector staging: xh[p] = x[p-128]-mean (p in [128,6128), zeros
// outside); A[m][q] = xh[16m+q]; Bp[n][q] = H[q-n-1] (q = k+n+1). Staging is fully
// vectorized: float4->half4 ds_write_b64 (was 17 scalar b16 writes/thread).
#define XH_N 6528
#define BSTRIDE 296
__global__ __launch_bounds__(384, 1) void conv_kernel(const float* __restrict__ x,
                                                      const float* __restrict__ means,
                                                      const float* __restrict__ Hg,
                                                      float* __restrict__ y) {
  int rc = blockIdx.x;
  int tid = threadIdx.x;
  int lane = tid & 63;
  int w = tid >> 6;
  __shared__ __align__(16) _Float16 xh[XH_N];
  __shared__ __align__(16) _Float16 Bp[16 * BSTRIDE];
  const float* xr = x + (size_t)rc * T_LEN;
  const float* Hrow = Hg + (size_t)rc * 256;
  float mean = means[rc];
  // xh: half4 chunk q covers halves [4q,4q+4) = x float4 chunk q-32 (minus mean)
  #pragma unroll
  for (int j = 0; j < 5; ++j) {
    int q = tid + 384 * j;
    if (q < 1632) {
      int c = q - 32;
      half4_t h;
      if (c >= 0 && c < 1500) {
        float4 vv = ((const float4*)xr)[c];
        h = (half4_t){ (_Float16)(vv.x - mean), (_Float16)(vv.y - mean),
                       (_Float16)(vv.z - mean), (_Float16)(vv.w - mean) };
      } else {
        h = (half4_t){ (_Float16)0.f, (_Float16)0.f, (_Float16)0.f, (_Float16)0.f };
      }
      *(half4_t*)((char*)xh + 8 * q) = h;
    }
  }
  // Bp: idx = chunk*16+n; thread writes half4 at Bp[n][4*qq..] = H[4*qq-n-1 ..]
  #pragma unroll
  for (int j = 0; j < 3; ++j) {
    int idx = tid + 384 * j;        // < 1152 = 72*16 exactly
    int n = idx & 15;
    int qq = idx >> 4;              // 0..71
    int s0 = 4 * qq - n - 1;
    half4_t h;
    #pragma unroll
    for (int e = 0; e < 4; ++e) {
      int s = s0 + e;
      float hv = (s >= 0 && s < 256) ? Hrow[s] : 0.f;
      h[e] = (_Float16)hv;
    }
    *(half4_t*)((char*)Bp + (size_t)n * (2 * BSTRIDE) + 8 * qq) = h;
  }
  __syncthreads();

  int l15 = lane & 15, l4 = lane >> 4;
  f32x4 acc0 = {0.f,0.f,0.f,0.f}, acc1 = {0.f,0.f,0.f,0.f};
  f32x4 acc2 = {0.f,0.f,0.f,0.f}, acc3 = {0.f,0.f,0.f,0.f};
  const _Float16* bbase = &Bp[BSTRIDE * l15 + 8 * l4];
  const _Float16* abase = &xh[16 * l15 + 8 * l4 + 1024 * w];
  #pragma unroll
  for (int kk = 0; kk < 9; ++kk) {
    half8 b = *(const half8*)(bbase + 32 * kk);
    half8 a0 = *(const half8*)(abase + 32 * kk);
    half8 a1 = *(const half8*)(abase + 256 + 32 * kk);
    half8 a2 = *(const half8*)(abase + 512 + 32 * kk);
    half8 a3 = *(const half8*)(abase + 768 + 32 * kk);
    acc0 = __builtin_amdgcn_mfma_f32_16x16x32_f16(a0, b, acc0, 0, 0, 0);
    acc1 = __builtin_amdgcn_mfma_f32_16x16x32_f16(a1, b, acc1, 0, 0, 0);
    acc2 = __builtin_amdgcn_mfma_f32_16x16x32_f16(a2, b, acc2, 0, 0, 0);
    acc3 = __builtin_amdgcn_mfma_f32_16x16x32_f16(a3, b, acc3, 0, 0, 0);
  }
  float* yr = y + (size_t)rc * T_LEN;
  #pragma unroll
  for (int i = 0; i < 4; ++i) {
    f32x4 a = (i == 0) ? acc0 : (i == 1) ? acc1 : (i == 2) ? acc2 : acc3;
    int mt = 4 * w + i;
    #pragma unroll
    for (int j = 0; j < 4; ++j) {
      int m = 16 * mt + 4 * l4 + j;
      if (m < 375) yr[16 * m + l15] = a[j];
    }
  }
}

extern "C" void kernel_launch(void* const* d_in, const int* in_sizes, int n_in,
                              void* d_out, int out_size, void* d_ws, size_t ws_size,
                              hipStream_t stream) {
  const float* x = (const float*)d_in[0];
  float* out = (float*)d_out;
  float* psd   = (float*)d_ws;                         //   528,384 f
  float* bary  = psd + (size_t)NROWS * F_BINS;         //     1,032 f
  float* H     = bary + CF;                            // 1,048,576 f
  float* means = H + (size_t)NROWS * 256;              //     4,096 f
  _Float16* Bf = (_Float16*)(means + NROWS);           //    65,536 f16 (16B-aligned)
  basis_kernel<<<32, 256, 0, stream>>>(Bf);
  psd_kernel<<<NROWS / PSD_ROWS, 512, 0, stream>>>(x, Bf, psd, means);
  bary_kernel<<<CF, 256, 0, stream>>>(psd, bary);
  filt_kernel<<<NROWS, 256, 0, stream>>>(psd, bary, H);
  conv_kernel<<<NROWS, 384, 0, stream>>>(x, means, H, out);
}